// Round 2
// baseline (1175.448 us; speedup 1.0000x reference)
//
#include <hip/hip_runtime.h>
#include <stdint.h>

typedef float f2 __attribute__((ext_vector_type(2)));

// res[l] = floor(16 * b^l), b = exp((ln512 - ln16)/15) in fp32 (rounds just above 2^(1/3),
// so boundary levels land at exact powers of two).
__constant__ float c_res[16] = {16.f, 20.f, 25.f, 32.f, 40.f, 50.f, 64.f, 80.f,
                                101.f, 128.f, 161.f, 203.f, 256.f, 322.f, 406.f, 512.f};

#define HASH_MASK ((1u << 19) - 1u)
#define P1 2654435761u
#define P2 805459861u

__global__ __launch_bounds__(256) void hash_encode_kernel(
    const float* __restrict__ x,
    const float* __restrict__ tables,
    float* __restrict__ out,
    float* __restrict__ mask_out,
    int n_points)
{
    int tid = blockIdx.x * 256 + threadIdx.x;
    int level = tid & 15;
    int p = tid >> 4;
    if (p >= n_points) return;

    // 16 lanes per point load the same 3 floats -> L1 broadcast.
    float x0 = x[3 * (size_t)p + 0];
    float x1 = x[3 * (size_t)p + 1];
    float x2 = x[3 * (size_t)p + 2];

    if (level == 0) {
        bool keep = (x0 >= 0.f) & (x0 <= 1.f) &
                    (x1 >= 0.f) & (x1 <= 1.f) &
                    (x2 >= 0.f) & (x2 <= 1.f);
        __builtin_nontemporal_store(keep ? 1.0f : 0.0f, &mask_out[p]);
    }

    // clip to [0,1]
    x0 = fminf(fmaxf(x0, 0.f), 1.f);
    x1 = fminf(fmaxf(x1, 0.f), 1.f);
    x2 = fminf(fmaxf(x2, 0.f), 1.f);

    float res  = c_res[level];
    float grid = 1.0f / res;                 // (box_max-box_min)/res, box=[0,1]

    float b0 = floorf(x0 / grid);
    float b1 = floorf(x1 / grid);
    float b2 = floorf(x2 / grid);

    float v0 = b0 * grid;
    float v1 = b1 * grid;
    float v2 = b2 * grid;

    float wx = (x0 - v0) / grid;
    float wy = (x1 - v1) / grid;
    float wz = (x2 - v2) / grid;

    uint32_t bx = (uint32_t)b0;
    uint32_t by = (uint32_t)b1;
    uint32_t bz = (uint32_t)b2;

    uint32_t hx0 = bx;            uint32_t hx1 = bx + 1u;
    uint32_t hy0 = by * P1;       uint32_t hy1 = hy0 + P1;   // (by+1)*P1 mod 2^32
    uint32_t hz0 = bz * P2;       uint32_t hz1 = hz0 + P2;

    const f2* __restrict__ tab =
        (const f2*)tables + ((size_t)level << 19);   // 2^19 float2 entries per level

    // corner bit order: bit2 = x-offset, bit1 = y-offset, bit0 = z-offset
    f2 e000 = tab[(hx0 ^ hy0 ^ hz0) & HASH_MASK];
    f2 e001 = tab[(hx0 ^ hy0 ^ hz1) & HASH_MASK];
    f2 e010 = tab[(hx0 ^ hy1 ^ hz0) & HASH_MASK];
    f2 e011 = tab[(hx0 ^ hy1 ^ hz1) & HASH_MASK];
    f2 e100 = tab[(hx1 ^ hy0 ^ hz0) & HASH_MASK];
    f2 e101 = tab[(hx1 ^ hy0 ^ hz1) & HASH_MASK];
    f2 e110 = tab[(hx1 ^ hy1 ^ hz0) & HASH_MASK];
    f2 e111 = tab[(hx1 ^ hy1 ^ hz1) & HASH_MASK];

    float owx = 1.f - wx, owy = 1.f - wy, owz = 1.f - wz;

    // lerp over x
    f2 c00 = e000 * owx + e100 * wx;
    f2 c01 = e001 * owx + e101 * wx;
    f2 c10 = e010 * owx + e110 * wx;
    f2 c11 = e011 * owx + e111 * wx;

    // lerp over y
    f2 c0 = c00 * owy + c10 * wy;
    f2 c1 = c01 * owy + c11 * wy;

    // lerp over z
    f2 cv = c0 * owz + c1 * wz;

    // out[p][level*2 .. level*2+1]; wave writes 512 contiguous bytes
    f2* dst = (f2*)(out + (size_t)p * 32) + level;
    __builtin_nontemporal_store(cv, dst);
}

extern "C" void kernel_launch(void* const* d_in, const int* in_sizes, int n_in,
                              void* d_out, int out_size, void* d_ws, size_t ws_size,
                              hipStream_t stream) {
    const float* x      = (const float*)d_in[0];
    const float* tables = (const float*)d_in[1];
    float* out = (float*)d_out;
    int n_points = in_sizes[0] / 3;
    float* mask_out = out + (size_t)n_points * 32;

    int total_threads = n_points * 16;
    int blocks = (total_threads + 255) / 256;
    hipLaunchKernelGGL(hash_encode_kernel, dim3(blocks), dim3(256), 0, stream,
                       x, tables, out, mask_out, n_points);
}

// Round 3
// 894.621 us; speedup vs baseline: 1.3139x; 1.3139x over previous
//
#include <hip/hip_runtime.h>
#include <stdint.h>

typedef float f2 __attribute__((ext_vector_type(2)));

// res[l] = floor(16 * b^l), b = exp((ln512 - ln16)/15) in fp32 (rounds just above 2^(1/3),
// so boundary levels land at exact powers of two).
__constant__ float c_res[16] = {16.f, 20.f, 25.f, 32.f, 40.f, 50.f, 64.f, 80.f,
                                101.f, 128.f, 161.f, 203.f, 256.f, 322.f, 406.f, 512.f};

#define HASH_MASK ((1u << 19) - 1u)
#define P1 2654435761u
#define P2 805459861u

// Grid layout: 2 phases (levels 0-7, then 8-15) x chunks x 8 levels.
// blockIdx.x % 8 == level % 8  ->  with round-robin block->XCD dispatch, each
// XCD's 4 MB L2 only ever holds ONE level's table (~<=4 MB) at a time:
// phase split keeps levels l and l+8 from being live simultaneously.
__global__ __launch_bounds__(256) void hash_encode_kernel(
    const float* __restrict__ x,
    const float* __restrict__ tables,
    float* __restrict__ out,
    float* __restrict__ mask_out,
    int n_points,
    int blocks_per_phase)   // chunks * 8
{
    int bid = blockIdx.x;
    int level_base = 0;
    if (bid >= blocks_per_phase) { bid -= blocks_per_phase; level_base = 8; }
    int level = (bid & 7) + level_base;
    int chunk = bid >> 3;
    int p = chunk * 256 + threadIdx.x;
    if (p >= n_points) return;

    // Streaming x read: nontemporal so it doesn't evict table lines from L2.
    float x0 = __builtin_nontemporal_load(&x[3 * (size_t)p + 0]);
    float x1 = __builtin_nontemporal_load(&x[3 * (size_t)p + 1]);
    float x2 = __builtin_nontemporal_load(&x[3 * (size_t)p + 2]);

    if (level == 0) {
        bool keep = (x0 >= 0.f) & (x0 <= 1.f) &
                    (x1 >= 0.f) & (x1 <= 1.f) &
                    (x2 >= 0.f) & (x2 <= 1.f);
        __builtin_nontemporal_store(keep ? 1.0f : 0.0f, &mask_out[p]);
    }

    // clip to [0,1]
    x0 = fminf(fmaxf(x0, 0.f), 1.f);
    x1 = fminf(fmaxf(x1, 0.f), 1.f);
    x2 = fminf(fmaxf(x2, 0.f), 1.f);

    float res  = c_res[level];
    float grid = 1.0f / res;

    float b0 = floorf(x0 / grid);
    float b1 = floorf(x1 / grid);
    float b2 = floorf(x2 / grid);

    float v0 = b0 * grid;
    float v1 = b1 * grid;
    float v2 = b2 * grid;

    float wx = (x0 - v0) / grid;
    float wy = (x1 - v1) / grid;
    float wz = (x2 - v2) / grid;

    uint32_t bx = (uint32_t)b0;
    uint32_t by = (uint32_t)b1;
    uint32_t bz = (uint32_t)b2;

    uint32_t hx0 = bx;            uint32_t hx1 = bx + 1u;
    uint32_t hy0 = by * P1;       uint32_t hy1 = hy0 + P1;   // (by+1)*P1 mod 2^32
    uint32_t hz0 = bz * P2;       uint32_t hz1 = hz0 + P2;

    const f2* __restrict__ tab =
        (const f2*)tables + ((size_t)level << 19);   // 2^19 float2 entries per level

    // corner bit order: bit2 = x-offset, bit1 = y-offset, bit0 = z-offset
    f2 e000 = tab[(hx0 ^ hy0 ^ hz0) & HASH_MASK];
    f2 e001 = tab[(hx0 ^ hy0 ^ hz1) & HASH_MASK];
    f2 e010 = tab[(hx0 ^ hy1 ^ hz0) & HASH_MASK];
    f2 e011 = tab[(hx0 ^ hy1 ^ hz1) & HASH_MASK];
    f2 e100 = tab[(hx1 ^ hy0 ^ hz0) & HASH_MASK];
    f2 e101 = tab[(hx1 ^ hy0 ^ hz1) & HASH_MASK];
    f2 e110 = tab[(hx1 ^ hy1 ^ hz0) & HASH_MASK];
    f2 e111 = tab[(hx1 ^ hy1 ^ hz1) & HASH_MASK];

    float owx = 1.f - wx, owy = 1.f - wy, owz = 1.f - wz;

    // trilinear lerp
    f2 c00 = e000 * owx + e100 * wx;
    f2 c01 = e001 * owx + e101 * wx;
    f2 c10 = e010 * owx + e110 * wx;
    f2 c11 = e011 * owx + e111 * wx;

    f2 c0 = c00 * owy + c10 * wy;
    f2 c1 = c01 * owy + c11 * wy;

    f2 cv = c0 * owz + c1 * wz;

    // out[p][level*2 .. level*2+1]; strided 8 B stores (128 B apart) — accepted
    // in exchange for per-XCD L2 table residency.
    f2* dst = (f2*)(out + (size_t)p * 32) + level;
    __builtin_nontemporal_store(cv, dst);
}

extern "C" void kernel_launch(void* const* d_in, const int* in_sizes, int n_in,
                              void* d_out, int out_size, void* d_ws, size_t ws_size,
                              hipStream_t stream) {
    const float* x      = (const float*)d_in[0];
    const float* tables = (const float*)d_in[1];
    float* out = (float*)d_out;
    int n_points = in_sizes[0] / 3;
    float* mask_out = out + (size_t)n_points * 32;

    int chunks = (n_points + 255) / 256;
    int blocks_per_phase = chunks * 8;
    int blocks = blocks_per_phase * 2;
    hipLaunchKernelGGL(hash_encode_kernel, dim3(blocks), dim3(256), 0, stream,
                       x, tables, out, mask_out, n_points, blocks_per_phase);
}

// Round 4
// 875.907 us; speedup vs baseline: 1.3420x; 1.0214x over previous
//
#include <hip/hip_runtime.h>
#include <stdint.h>

typedef float f2 __attribute__((ext_vector_type(2)));

// res[l] = floor(16 * b^l), b = exp((ln512 - ln16)/15) in fp32.
__constant__ float c_res[16] = {16.f, 20.f, 25.f, 32.f, 40.f, 50.f, 64.f, 80.f,
                                101.f, 128.f, 161.f, 203.f, 256.f, 322.f, 406.f, 512.f};

#define HASH_MASK ((1u << 19) - 1u)
#define P1 2654435761u
#define P2 805459861u
#define PTS_PER_THREAD 2

// Grid: 2 phases (levels 0-7, 8-15) x chunks x 8 levels; blockIdx%8 == level%8
// keeps one level's table per XCD L2 (round-robin dispatch), phase split keeps
// levels l and l+8 from being live together. Each thread handles 2 points at
// one level -> 16 outstanding 8B gathers/thread to hide L2 latency.
__global__ __launch_bounds__(256) void hash_encode_kernel(
    const float* __restrict__ x,
    const float* __restrict__ tables,
    float* __restrict__ out,
    float* __restrict__ mask_out,
    int n_points,
    int blocks_per_phase)
{
    int bid = blockIdx.x;
    int level_base = 0;
    if (bid >= blocks_per_phase) { bid -= blocks_per_phase; level_base = 8; }
    int level = (bid & 7) + level_base;
    int chunk = bid >> 3;

    float res  = c_res[level];
    float grid = 1.0f / res;
    const f2* __restrict__ tab =
        (const f2*)tables + ((size_t)level << 19);   // 2^19 float2 per level

    int pbase = chunk * (256 * PTS_PER_THREAD) + threadIdx.x;

    uint32_t idx[PTS_PER_THREAD][8];
    float wx[PTS_PER_THREAD], wy[PTS_PER_THREAD], wz[PTS_PER_THREAD];
    bool valid[PTS_PER_THREAD];
    int pp[PTS_PER_THREAD];

    #pragma unroll
    for (int s = 0; s < PTS_PER_THREAD; ++s) {
        int p = pbase + s * 256;
        pp[s] = p;
        valid[s] = (p < n_points);
        int pc = valid[s] ? p : 0;

        float x0 = __builtin_nontemporal_load(&x[3 * (size_t)pc + 0]);
        float x1 = __builtin_nontemporal_load(&x[3 * (size_t)pc + 1]);
        float x2 = __builtin_nontemporal_load(&x[3 * (size_t)pc + 2]);

        if (level == 0 && valid[s]) {
            bool keep = (x0 >= 0.f) & (x0 <= 1.f) &
                        (x1 >= 0.f) & (x1 <= 1.f) &
                        (x2 >= 0.f) & (x2 <= 1.f);
            __builtin_nontemporal_store(keep ? 1.0f : 0.0f, &mask_out[pc]);
        }

        x0 = fminf(fmaxf(x0, 0.f), 1.f);
        x1 = fminf(fmaxf(x1, 0.f), 1.f);
        x2 = fminf(fmaxf(x2, 0.f), 1.f);

        float b0 = floorf(x0 / grid);
        float b1 = floorf(x1 / grid);
        float b2 = floorf(x2 / grid);

        wx[s] = (x0 - b0 * grid) / grid;
        wy[s] = (x1 - b1 * grid) / grid;
        wz[s] = (x2 - b2 * grid) / grid;

        uint32_t bx = (uint32_t)b0;
        uint32_t by = (uint32_t)b1;
        uint32_t bz = (uint32_t)b2;

        uint32_t hx0 = bx;        uint32_t hx1 = bx + 1u;
        uint32_t hy0 = by * P1;   uint32_t hy1 = hy0 + P1;
        uint32_t hz0 = bz * P2;   uint32_t hz1 = hz0 + P2;

        idx[s][0] = (hx0 ^ hy0 ^ hz0) & HASH_MASK;
        idx[s][1] = (hx0 ^ hy0 ^ hz1) & HASH_MASK;
        idx[s][2] = (hx0 ^ hy1 ^ hz0) & HASH_MASK;
        idx[s][3] = (hx0 ^ hy1 ^ hz1) & HASH_MASK;
        idx[s][4] = (hx1 ^ hy0 ^ hz0) & HASH_MASK;
        idx[s][5] = (hx1 ^ hy0 ^ hz1) & HASH_MASK;
        idx[s][6] = (hx1 ^ hy1 ^ hz0) & HASH_MASK;
        idx[s][7] = (hx1 ^ hy1 ^ hz1) & HASH_MASK;
    }

    // Issue all 16 gathers before any consumption.
    f2 e[PTS_PER_THREAD][8];
    #pragma unroll
    for (int s = 0; s < PTS_PER_THREAD; ++s)
        #pragma unroll
        for (int c = 0; c < 8; ++c)
            e[s][c] = tab[idx[s][c]];

    #pragma unroll
    for (int s = 0; s < PTS_PER_THREAD; ++s) {
        float owx = 1.f - wx[s], owy = 1.f - wy[s], owz = 1.f - wz[s];

        f2 c00 = e[s][0] * owx + e[s][4] * wx[s];
        f2 c01 = e[s][1] * owx + e[s][5] * wx[s];
        f2 c10 = e[s][2] * owx + e[s][6] * wx[s];
        f2 c11 = e[s][3] * owx + e[s][7] * wx[s];

        f2 c0 = c00 * owy + c10 * wy[s];
        f2 c1 = c01 * owy + c11 * wy[s];

        f2 cv = c0 * owz + c1 * wz[s];

        if (valid[s]) {
            f2* dst = (f2*)(out + (size_t)pp[s] * 32) + level;
            __builtin_nontemporal_store(cv, dst);
        }
    }
}

extern "C" void kernel_launch(void* const* d_in, const int* in_sizes, int n_in,
                              void* d_out, int out_size, void* d_ws, size_t ws_size,
                              hipStream_t stream) {
    const float* x      = (const float*)d_in[0];
    const float* tables = (const float*)d_in[1];
    float* out = (float*)d_out;
    int n_points = in_sizes[0] / 3;
    float* mask_out = out + (size_t)n_points * 32;

    int chunks = (n_points + 256 * PTS_PER_THREAD - 1) / (256 * PTS_PER_THREAD);
    int blocks_per_phase = chunks * 8;
    int blocks = blocks_per_phase * 2;
    hipLaunchKernelGGL(hash_encode_kernel, dim3(blocks), dim3(256), 0, stream,
                       x, tables, out, mask_out, n_points, blocks_per_phase);
}